// Round 4
// baseline (635.907 us; speedup 1.0000x reference)
//
#include <hip/hip_runtime.h>
#include <hip/hip_bf16.h>
#include <stdint.h>

#define T_TOK 4096
#define H_DIM 2048
#define I_DIM 1024
#define E_NUM 8

using bf16x8  = __attribute__((ext_vector_type(8))) __bf16;
using f32x4   = __attribute__((ext_vector_type(4))) float;
using ushort8 = __attribute__((ext_vector_type(8))) unsigned short;

// RTNE float->bf16
__device__ __forceinline__ unsigned short f2bf(float f) {
  unsigned int u = __float_as_uint(f);
  u += 0x7fffu + ((u >> 16) & 1u);
  return (unsigned short)(u >> 16);
}

// async global->LDS, 16B per lane. LDS dest must be wave-uniform base + lane*16
// (linear); global src may be per-lane.
__device__ __forceinline__ void gload16(const unsigned short* g, unsigned short* l) {
  __builtin_amdgcn_global_load_lds(
      (const __attribute__((address_space(1))) unsigned int*)(g),
      (__attribute__((address_space(3))) unsigned int*)(l), 16, 0, 0);
}

// ---------------- weight pre-convert: w1 fp32 -> bf16, de-interleaved [E][2][I][H] ----------------
__global__ void k_cvt_w1(const float* __restrict__ w1, unsigned short* __restrict__ w1b) {
  size_t idx = (size_t)blockIdx.x * 256 + threadIdx.x;
  size_t d = idx * 8;                      // flat dst over [E][2][I][H]
  int h = (int)(d & (size_t)(H_DIM - 1));
  size_t rem = d >> 11;                    // / H_DIM
  int i = (int)(rem & (size_t)(I_DIM - 1));
  size_t rem2 = rem >> 10;                 // / I_DIM
  int gu = (int)(rem2 & 1);
  int e = (int)(rem2 >> 1);
  const float* src = w1 + (((size_t)e * 2 * I_DIM + 2 * i + gu) * H_DIM + h);
  float4 v0 = *reinterpret_cast<const float4*>(src);
  float4 v1 = *reinterpret_cast<const float4*>(src + 4);
  ushort8 b;
  b[0] = f2bf(v0.x); b[1] = f2bf(v0.y); b[2] = f2bf(v0.z); b[3] = f2bf(v0.w);
  b[4] = f2bf(v1.x); b[5] = f2bf(v1.y); b[6] = f2bf(v1.z); b[7] = f2bf(v1.w);
  *reinterpret_cast<ushort8*>(w1b + d) = b;
}

// ---------------- weight pre-convert: w2 fp32 -> bf16 flat ----------------
__global__ void k_cvt_w2(const float* __restrict__ w2, unsigned short* __restrict__ w2b) {
  size_t d = ((size_t)blockIdx.x * 256 + threadIdx.x) * 8;
  float4 v0 = *reinterpret_cast<const float4*>(w2 + d);
  float4 v1 = *reinterpret_cast<const float4*>(w2 + d + 4);
  ushort8 b;
  b[0] = f2bf(v0.x); b[1] = f2bf(v0.y); b[2] = f2bf(v0.z); b[3] = f2bf(v0.w);
  b[4] = f2bf(v1.x); b[5] = f2bf(v1.y); b[6] = f2bf(v1.z); b[7] = f2bf(v1.w);
  *reinterpret_cast<ushort8*>(w2b + d) = b;
}

// ---------------- router: logits -> softmax -> top2, fused x->bf16 cast ----------------
__global__ void k_router(const float* __restrict__ x, const float* __restrict__ rw,
                         float* __restrict__ gates, int* __restrict__ idxs,
                         unsigned int* __restrict__ counts, unsigned short* __restrict__ xb) {
  int t = blockIdx.x;
  int lane = threadIdx.x;  // 64 threads = 1 wave
  float acc[E_NUM];
#pragma unroll
  for (int e = 0; e < E_NUM; e++) acc[e] = 0.f;
  const float* xrow = x + (size_t)t * H_DIM;
  for (int h = lane; h < H_DIM; h += 64) {
    float xv = xrow[h];
    xb[(size_t)t * H_DIM + h] = f2bf(xv);
#pragma unroll
    for (int e = 0; e < E_NUM; e++) acc[e] += xv * rw[e * H_DIM + h];
  }
#pragma unroll
  for (int e = 0; e < E_NUM; e++) {
#pragma unroll
    for (int off = 32; off >= 1; off >>= 1) acc[e] += __shfl_xor(acc[e], off, 64);
  }
  if (lane == 0) {
    float mx = acc[0];
#pragma unroll
    for (int e = 1; e < E_NUM; e++) mx = fmaxf(mx, acc[e]);
    float p[E_NUM], s = 0.f;
#pragma unroll
    for (int e = 0; e < E_NUM; e++) { p[e] = __expf(acc[e] - mx); s += p[e]; }
    float inv = 1.f / s;
#pragma unroll
    for (int e = 0; e < E_NUM; e++) p[e] *= inv;
    int i1 = 0, i2 = 0; float m1 = -1.f, m2 = -1.f;
#pragma unroll
    for (int e = 0; e < E_NUM; e++) {
      float v = p[e];
      if (v > m1)      { m2 = m1; i2 = i1; m1 = v; i1 = e; }
      else if (v > m2) { m2 = v; i2 = e; }
    }
    gates[t * 2 + 0] = m1; gates[t * 2 + 1] = m2;
    idxs[t * 2 + 0] = i1;  idxs[t * 2 + 1] = i2;
    atomicAdd(&counts[i1], 1u);
    atomicAdd(&counts[i2], 1u);
  }
}

// ---------------- prefix offsets over 8 experts ----------------
__global__ void k_offsets(const unsigned int* __restrict__ counts,
                          unsigned int* __restrict__ off, unsigned int* __restrict__ cursor) {
  if (threadIdx.x == 0 && blockIdx.x == 0) {
    unsigned int o = 0;
    for (int e = 0; e < E_NUM; e++) { off[e] = o; cursor[e] = o; o += counts[e]; }
  }
}

// ---------------- scatter tokens into per-expert compact lists ----------------
__global__ void k_scatter(const float* __restrict__ gates, const int* __restrict__ idxs,
                          unsigned int* __restrict__ cursor,
                          int* __restrict__ rowlist, float* __restrict__ rowgate) {
  int t = blockIdx.x * blockDim.x + threadIdx.x;
  if (t >= T_TOK) return;
#pragma unroll
  for (int k = 0; k < 2; k++) {
    int e = idxs[t * 2 + k];
    unsigned int pos = atomicAdd(&cursor[e], 1u);
    rowlist[pos] = t;
    rowgate[pos] = gates[t * 2 + k];
  }
}

// ---------------- GEMM1: h = silu(x@w1_g^T) * (x@w1_u^T), m97-style gload_lds ----------------
// tile: 128 rows x 64 i-cols, BK=32, 4 waves (2x2). LDS linear (no pad) for gload_lds.
__launch_bounds__(256, 3)
__global__ void k_gemm1(const unsigned short* __restrict__ xb, const unsigned short* __restrict__ w1b,
                        const unsigned int* __restrict__ off, const unsigned int* __restrict__ counts,
                        const int* __restrict__ rowlist, unsigned short* __restrict__ hc) {
  int e = blockIdx.z;
  unsigned int cnt = counts[e];
  unsigned int rb = blockIdx.y;
  if (rb * 128u >= cnt) return;
  unsigned int o = off[e];
  int i0 = blockIdx.x * 64;

  __shared__ unsigned short a_lds[128 * 32];   // 8KB
  __shared__ unsigned short bg_lds[64 * 32];   // 4KB
  __shared__ unsigned short bu_lds[64 * 32];   // 4KB

  int tid = threadIdx.x, lane = tid & 63, wave = tid >> 6;
  int wr = wave >> 1, wc = wave & 1;

  // A gather: each lane owns one fixed (row, col-quad); per K-step only k0 advances
  const unsigned short* aptr[2];
  unsigned short* alds[2];
#pragma unroll
  for (int it = 0; it < 2; it++) {
    int flat = wave * 128 + it * 64 + lane;
    int row = flat >> 2, colq = flat & 3;
    unsigned int pos = rb * 128u + (unsigned int)row;
    unsigned int gp = o + (pos < cnt ? pos : cnt - 1u);
    int tok = rowlist[gp];
    aptr[it] = xb + (size_t)tok * H_DIM + colq * 8;
    alds[it] = &a_lds[(wave * 2 + it) * 512];
  }
  // B: linear bf16 weight rows (de-interleaved layout)
  int flatB = wave * 64 + lane;
  int brow = flatB >> 2, bcolq = flatB & 3;
  const unsigned short* bptr_g = w1b + ((size_t)(e * 2 + 0) * I_DIM + i0 + brow) * H_DIM + bcolq * 8;
  const unsigned short* bptr_u = w1b + ((size_t)(e * 2 + 1) * I_DIM + i0 + brow) * H_DIM + bcolq * 8;
  unsigned short* blds_g = &bg_lds[wave * 512];
  unsigned short* blds_u = &bu_lds[wave * 512];

  f32x4 accg[4][2], accu[4][2];
#pragma unroll
  for (int m = 0; m < 4; m++)
#pragma unroll
    for (int n = 0; n < 2; n++) {
      accg[m][n] = f32x4{0.f, 0.f, 0.f, 0.f};
      accu[m][n] = f32x4{0.f, 0.f, 0.f, 0.f};
    }

  for (int k0 = 0; k0 < H_DIM; k0 += 32) {
    __syncthreads();
    gload16(aptr[0] + k0, alds[0]);
    gload16(aptr[1] + k0, alds[1]);
    gload16(bptr_g + k0, blds_g);
    gload16(bptr_u + k0, blds_u);
    __syncthreads();  // compiler drains vmcnt(0) before s_barrier -> LDS ready

    bf16x8 af[4], bgf[2], buf_[2];
#pragma unroll
    for (int m = 0; m < 4; m++) {
      int row = wr * 64 + m * 16 + (lane & 15);
      af[m] = *reinterpret_cast<const bf16x8*>(&a_lds[row * 32 + (lane >> 4) * 8]);
    }
#pragma unroll
    for (int n = 0; n < 2; n++) {
      int c = wc * 32 + n * 16 + (lane & 15);
      bgf[n]  = *reinterpret_cast<const bf16x8*>(&bg_lds[c * 32 + (lane >> 4) * 8]);
      buf_[n] = *reinterpret_cast<const bf16x8*>(&bu_lds[c * 32 + (lane >> 4) * 8]);
    }
#pragma unroll
    for (int m = 0; m < 4; m++)
#pragma unroll
      for (int n = 0; n < 2; n++) {
        accg[m][n] = __builtin_amdgcn_mfma_f32_16x16x32_bf16(af[m], bgf[n],  accg[m][n], 0, 0, 0);
        accu[m][n] = __builtin_amdgcn_mfma_f32_16x16x32_bf16(af[m], buf_[n], accu[m][n], 0, 0, 0);
      }
  }

  // epilogue: h = u * silu(g), store bf16
#pragma unroll
  for (int m = 0; m < 4; m++)
#pragma unroll
    for (int n = 0; n < 2; n++)
#pragma unroll
      for (int r = 0; r < 4; r++) {
        unsigned int grow = rb * 128u + wr * 64 + m * 16 + (lane >> 4) * 4 + r;
        if (grow < cnt) {
          float g = accg[m][n][r], u = accu[m][n][r];
          float h = u * g / (1.f + __expf(-g));
          int ic = i0 + wc * 32 + n * 16 + (lane & 15);
          hc[(size_t)(o + grow) * I_DIM + ic] = f2bf(h);
        }
      }
}

// ---------------- GEMM2: out[tok] += gate * (h @ w2[e]^T), m97-style ----------------
// tile: 128 rows x 128 h-cols, BK=32, 4 waves (2x2), atomic scatter epilogue
__launch_bounds__(256, 3)
__global__ void k_gemm2(const unsigned short* __restrict__ hc, const unsigned short* __restrict__ w2b,
                        const unsigned int* __restrict__ off, const unsigned int* __restrict__ counts,
                        const int* __restrict__ rowlist, const float* __restrict__ rowgate,
                        float* __restrict__ out) {
  int e = blockIdx.z;
  unsigned int cnt = counts[e];
  unsigned int rb = blockIdx.y;
  if (rb * 128u >= cnt) return;
  unsigned int o = off[e];
  int h0 = blockIdx.x * 128;

  __shared__ unsigned short a_lds[128 * 32];  // 8KB
  __shared__ unsigned short b_lds[128 * 32];  // 8KB

  int tid = threadIdx.x, lane = tid & 63, wave = tid >> 6;
  int wr = wave >> 1, wc = wave & 1;

  const unsigned short* aptr[2];
  const unsigned short* bptr[2];
  unsigned short *alds[2], *blds[2];
#pragma unroll
  for (int it = 0; it < 2; it++) {
    int flat = wave * 128 + it * 64 + lane;
    int row = flat >> 2, colq = flat & 3;
    unsigned int pos = rb * 128u + (unsigned int)row;
    unsigned int posc = (pos < cnt ? pos : cnt - 1u);
    aptr[it] = hc + (size_t)(o + posc) * I_DIM + colq * 8;  // h rows expert-contiguous
    bptr[it] = w2b + ((size_t)e * H_DIM + h0 + row) * I_DIM + colq * 8;
    alds[it] = &a_lds[(wave * 2 + it) * 512];
    blds[it] = &b_lds[(wave * 2 + it) * 512];
  }

  f32x4 acc[4][4];
#pragma unroll
  for (int m = 0; m < 4; m++)
#pragma unroll
    for (int n = 0; n < 4; n++) acc[m][n] = f32x4{0.f, 0.f, 0.f, 0.f};

  for (int k0 = 0; k0 < I_DIM; k0 += 32) {
    __syncthreads();
    gload16(aptr[0] + k0, alds[0]);
    gload16(aptr[1] + k0, alds[1]);
    gload16(bptr[0] + k0, blds[0]);
    gload16(bptr[1] + k0, blds[1]);
    __syncthreads();

    bf16x8 af[4], bf[4];
#pragma unroll
    for (int m = 0; m < 4; m++) {
      int row = wr * 64 + m * 16 + (lane & 15);
      af[m] = *reinterpret_cast<const bf16x8*>(&a_lds[row * 32 + (lane >> 4) * 8]);
    }
#pragma unroll
    for (int n = 0; n < 4; n++) {
      int c = wc * 64 + n * 16 + (lane & 15);
      bf[n] = *reinterpret_cast<const bf16x8*>(&b_lds[c * 32 + (lane >> 4) * 8]);
    }
#pragma unroll
    for (int m = 0; m < 4; m++)
#pragma unroll
      for (int n = 0; n < 4; n++)
        acc[m][n] = __builtin_amdgcn_mfma_f32_16x16x32_bf16(af[m], bf[n], acc[m][n], 0, 0, 0);
  }

  // epilogue: scatter gate-weighted rows into out with fp32 atomics (exactly 2 adds/elem)
#pragma unroll
  for (int m = 0; m < 4; m++)
#pragma unroll
    for (int r = 0; r < 4; r++) {
      unsigned int grow = rb * 128u + wr * 64 + m * 16 + (lane >> 4) * 4 + r;
      if (grow < cnt) {
        int tok = rowlist[o + grow];
        float gate = rowgate[o + grow];
        float* orow = out + (size_t)tok * H_DIM + h0 + wc * 64;
#pragma unroll
        for (int n = 0; n < 4; n++) {
          atomicAdd(&orow[n * 16 + (lane & 15)], gate * acc[m][n][r]);
        }
      }
    }
}

extern "C" void kernel_launch(void* const* d_in, const int* in_sizes, int n_in,
                              void* d_out, int out_size, void* d_ws, size_t ws_size,
                              hipStream_t stream) {
  const float* x  = (const float*)d_in[0];
  const float* rw = (const float*)d_in[1];
  const float* w1 = (const float*)d_in[2];
  const float* w2 = (const float*)d_in[3];
  float* out = (float*)d_out;

  char* ws = (char*)d_ws;
  unsigned int* counts = (unsigned int*)(ws + 0);
  unsigned int* cursor = (unsigned int*)(ws + 64);
  unsigned int* off    = (unsigned int*)(ws + 128);
  float* gates   = (float*)(ws + 4096);
  int*   idxs    = (int*)(ws + 4096 + 32768);
  int*   rowlist = (int*)(ws + 4096 + 65536);
  float* rowgate = (float*)(ws + 4096 + 98304);
  unsigned short* xb  = (unsigned short*)(ws + (1ull << 20));    // 16 MiB @ 1 MiB
  unsigned short* hc  = (unsigned short*)(ws + (17ull << 20));   // 16 MiB @ 17 MiB
  unsigned short* w1b = (unsigned short*)(ws + (34ull << 20));   // 64 MiB @ 34 MiB
  unsigned short* w2b = (unsigned short*)(ws + (100ull << 20));  // 32 MiB @ 100 MiB

  hipMemsetAsync(ws, 0, 4096, stream);
  hipMemsetAsync(d_out, 0, (size_t)out_size * sizeof(float), stream);

  // one-shot weight converts (streaming, ~300 MB total traffic)
  k_cvt_w1<<<(E_NUM * 2 * I_DIM * (H_DIM / 8) + 255) / 256, 256, 0, stream>>>(w1, w1b);
  k_cvt_w2<<<(E_NUM * H_DIM * (I_DIM / 8) + 255) / 256, 256, 0, stream>>>(w2, w2b);

  k_router<<<T_TOK, 64, 0, stream>>>(x, rw, gates, idxs, counts, xb);
  k_offsets<<<1, 64, 0, stream>>>(counts, off, cursor);
  k_scatter<<<T_TOK / 256, 256, 0, stream>>>(gates, idxs, cursor, rowlist, rowgate);
  k_gemm1<<<dim3(I_DIM / 64, T_TOK / 128, E_NUM), 256, 0, stream>>>(xb, w1b, off, counts, rowlist, hc);
  k_gemm2<<<dim3(H_DIM / 128, T_TOK / 128, E_NUM), 256, 0, stream>>>(hc, w2b, off, counts, rowlist, rowgate, out);
}

// Round 5
// 600.752 us; speedup vs baseline: 1.0585x; 1.0585x over previous
//
#include <hip/hip_runtime.h>
#include <hip/hip_bf16.h>
#include <stdint.h>

#define T_TOK 4096
#define H_DIM 2048
#define I_DIM 1024
#define E_NUM 8

using bf16x8  = __attribute__((ext_vector_type(8))) __bf16;
using f32x4   = __attribute__((ext_vector_type(4))) float;
using ushort8 = __attribute__((ext_vector_type(8))) unsigned short;

// RTNE float->bf16
__device__ __forceinline__ unsigned short f2bf(float f) {
  unsigned int u = __float_as_uint(f);
  u += 0x7fffu + ((u >> 16) & 1u);
  return (unsigned short)(u >> 16);
}

// async global->LDS, 16B/lane; LDS dest = wave-uniform base + lane*16 (linear)
__device__ __forceinline__ void gload16(const unsigned short* g, unsigned short* l) {
  __builtin_amdgcn_global_load_lds(
      (const __attribute__((address_space(1))) unsigned int*)(g),
      (__attribute__((address_space(3))) unsigned int*)(l), 16, 0, 0);
}

// element offset into a [rows][32]-bf16 tile with q-quad XOR swizzle
// (physical quad = logical quad ^ ((row>>1)&3); involution, both-sides applied)
#define SWZ(row, qg) (((row) * 32) + ((((qg) ^ (((row) >> 1) & 3))) * 8))

// ---------------- weight pre-convert: w1 fp32 -> bf16, de-interleaved [E][2][I][H] ----------------
__global__ void k_cvt_w1(const float* __restrict__ w1, unsigned short* __restrict__ w1b) {
  size_t idx = (size_t)blockIdx.x * 256 + threadIdx.x;
  size_t d = idx * 8;                      // flat dst over [E][2][I][H]
  int h = (int)(d & (size_t)(H_DIM - 1));
  size_t rem = d >> 11;
  int i = (int)(rem & (size_t)(I_DIM - 1));
  size_t rem2 = rem >> 10;
  int gu = (int)(rem2 & 1);
  int e = (int)(rem2 >> 1);
  const float* src = w1 + (((size_t)e * 2 * I_DIM + 2 * i + gu) * H_DIM + h);
  float4 v0 = *reinterpret_cast<const float4*>(src);
  float4 v1 = *reinterpret_cast<const float4*>(src + 4);
  ushort8 b;
  b[0] = f2bf(v0.x); b[1] = f2bf(v0.y); b[2] = f2bf(v0.z); b[3] = f2bf(v0.w);
  b[4] = f2bf(v1.x); b[5] = f2bf(v1.y); b[6] = f2bf(v1.z); b[7] = f2bf(v1.w);
  *reinterpret_cast<ushort8*>(w1b + d) = b;
}

__global__ void k_cvt_w2(const float* __restrict__ w2, unsigned short* __restrict__ w2b) {
  size_t d = ((size_t)blockIdx.x * 256 + threadIdx.x) * 8;
  float4 v0 = *reinterpret_cast<const float4*>(w2 + d);
  float4 v1 = *reinterpret_cast<const float4*>(w2 + d + 4);
  ushort8 b;
  b[0] = f2bf(v0.x); b[1] = f2bf(v0.y); b[2] = f2bf(v0.z); b[3] = f2bf(v0.w);
  b[4] = f2bf(v1.x); b[5] = f2bf(v1.y); b[6] = f2bf(v1.z); b[7] = f2bf(v1.w);
  *reinterpret_cast<ushort8*>(w2b + d) = b;
}

// ---------------- router ----------------
__global__ void k_router(const float* __restrict__ x, const float* __restrict__ rw,
                         float* __restrict__ gates, int* __restrict__ idxs,
                         unsigned int* __restrict__ counts, unsigned short* __restrict__ xb) {
  int t = blockIdx.x;
  int lane = threadIdx.x;  // 64 = 1 wave
  float acc[E_NUM];
#pragma unroll
  for (int e = 0; e < E_NUM; e++) acc[e] = 0.f;
  const float* xrow = x + (size_t)t * H_DIM;
  for (int h = lane; h < H_DIM; h += 64) {
    float xv = xrow[h];
    xb[(size_t)t * H_DIM + h] = f2bf(xv);
#pragma unroll
    for (int e = 0; e < E_NUM; e++) acc[e] += xv * rw[e * H_DIM + h];
  }
#pragma unroll
  for (int e = 0; e < E_NUM; e++) {
#pragma unroll
    for (int off = 32; off >= 1; off >>= 1) acc[e] += __shfl_xor(acc[e], off, 64);
  }
  if (lane == 0) {
    float mx = acc[0];
#pragma unroll
    for (int e = 1; e < E_NUM; e++) mx = fmaxf(mx, acc[e]);
    float p[E_NUM], s = 0.f;
#pragma unroll
    for (int e = 0; e < E_NUM; e++) { p[e] = __expf(acc[e] - mx); s += p[e]; }
    float inv = 1.f / s;
#pragma unroll
    for (int e = 0; e < E_NUM; e++) p[e] *= inv;
    int i1 = 0, i2 = 0; float m1 = -1.f, m2 = -1.f;
#pragma unroll
    for (int e = 0; e < E_NUM; e++) {
      float v = p[e];
      if (v > m1)      { m2 = m1; i2 = i1; m1 = v; i1 = e; }
      else if (v > m2) { m2 = v; i2 = e; }
    }
    gates[t * 2 + 0] = m1; gates[t * 2 + 1] = m2;
    idxs[t * 2 + 0] = i1;  idxs[t * 2 + 1] = i2;
    atomicAdd(&counts[i1], 1u);
    atomicAdd(&counts[i2], 1u);
  }
}

__global__ void k_offsets(const unsigned int* __restrict__ counts,
                          unsigned int* __restrict__ off, unsigned int* __restrict__ cursor) {
  if (threadIdx.x == 0 && blockIdx.x == 0) {
    unsigned int o = 0;
    for (int e = 0; e < E_NUM; e++) { off[e] = o; cursor[e] = o; o += counts[e]; }
  }
}

__global__ void k_scatter(const float* __restrict__ gates, const int* __restrict__ idxs,
                          unsigned int* __restrict__ cursor,
                          int* __restrict__ rowlist, float* __restrict__ rowgate,
                          int* __restrict__ tok2slot) {
  int t = blockIdx.x * blockDim.x + threadIdx.x;
  if (t >= T_TOK) return;
#pragma unroll
  for (int k = 0; k < 2; k++) {
    int e = idxs[t * 2 + k];
    unsigned int pos = atomicAdd(&cursor[e], 1u);
    rowlist[pos] = t;
    rowgate[pos] = gates[t * 2 + k];
    tok2slot[t * 2 + k] = (int)pos;
  }
}

// ---------------- GEMM1: h = silu(x@w1_g^T)*(x@w1_u^T) ----------------
// tile 128 rows x 128 i-cols (256 w1 f-rows), BK=32, 4 waves 2x2,
// LDS double-buffer + next-tile prefetch (T3-min), swizzled staging.
__launch_bounds__(256, 2)
__global__ void k_gemm1(const unsigned short* __restrict__ xb, const unsigned short* __restrict__ w1b,
                        const unsigned int* __restrict__ off, const unsigned int* __restrict__ counts,
                        const int* __restrict__ rowlist, unsigned short* __restrict__ hc) {
  int e = blockIdx.z;
  unsigned int cnt = counts[e];
  unsigned int rb = blockIdx.y;
  if (rb * 128u >= cnt) return;
  unsigned int o = off[e];
  int i0 = blockIdx.x * 128;

  // per buffer: A[128][32] @0, Bg[128][32] @4096, Bu[128][32] @8192 (shorts)
  __shared__ unsigned short lds[2][12288];  // 48 KB

  int tid = threadIdx.x, lane = tid & 63, wave = tid >> 6;
  int wr = wave >> 1, wc = wave & 1;

  const unsigned short *aptr[2], *bgptr[2], *buptr[2];
#pragma unroll
  for (int it = 0; it < 2; it++) {
    int flat = it * 256 + tid;
    int row = flat >> 2, q = flat & 3;
    int qs = q ^ ((row >> 1) & 3);  // pre-swizzled source quad
    unsigned int pos = rb * 128u + (unsigned int)row;
    unsigned int gp = o + (pos < cnt ? pos : cnt - 1u);
    int tok = rowlist[gp];
    aptr[it]  = xb + (size_t)tok * H_DIM + qs * 8;
    bgptr[it] = w1b + ((size_t)(e * 2 + 0) * I_DIM + i0 + row) * H_DIM + qs * 8;
    buptr[it] = w1b + ((size_t)(e * 2 + 1) * I_DIM + i0 + row) * H_DIM + qs * 8;
  }

  f32x4 accg[4][4], accu[4][4];
#pragma unroll
  for (int m = 0; m < 4; m++)
#pragma unroll
    for (int n = 0; n < 4; n++) {
      accg[m][n] = f32x4{0.f, 0.f, 0.f, 0.f};
      accu[m][n] = f32x4{0.f, 0.f, 0.f, 0.f};
    }

  // prologue stage into buf0
#pragma unroll
  for (int it = 0; it < 2; it++) {
    gload16(aptr[it],  &lds[0][(it * 256 + tid) * 8]);
    gload16(bgptr[it], &lds[0][4096 + (it * 256 + tid) * 8]);
    gload16(buptr[it], &lds[0][8192 + (it * 256 + tid) * 8]);
  }

  int cur = 0;
  int qg = lane >> 4;
  for (int step = 0; step < H_DIM / 32; ++step) {
    __syncthreads();  // drains vmcnt(0)+lgkmcnt before barrier: buf[cur] ready
    if (step + 1 < H_DIM / 32) {
      int k0 = (step + 1) * 32;
#pragma unroll
      for (int it = 0; it < 2; it++) {
        gload16(aptr[it] + k0,  &lds[cur ^ 1][(it * 256 + tid) * 8]);
        gload16(bgptr[it] + k0, &lds[cur ^ 1][4096 + (it * 256 + tid) * 8]);
        gload16(buptr[it] + k0, &lds[cur ^ 1][8192 + (it * 256 + tid) * 8]);
      }
    }
    bf16x8 af[4], bgf[4], buf_[4];
#pragma unroll
    for (int m = 0; m < 4; m++) {
      int row = wr * 64 + m * 16 + (lane & 15);
      af[m] = *reinterpret_cast<const bf16x8*>(&lds[cur][SWZ(row, qg)]);
    }
#pragma unroll
    for (int n = 0; n < 4; n++) {
      int c = wc * 64 + n * 16 + (lane & 15);
      bgf[n]  = *reinterpret_cast<const bf16x8*>(&lds[cur][4096 + SWZ(c, qg)]);
      buf_[n] = *reinterpret_cast<const bf16x8*>(&lds[cur][8192 + SWZ(c, qg)]);
    }
#pragma unroll
    for (int m = 0; m < 4; m++)
#pragma unroll
      for (int n = 0; n < 4; n++) {
        accg[m][n] = __builtin_amdgcn_mfma_f32_16x16x32_bf16(af[m], bgf[n],  accg[m][n], 0, 0, 0);
        accu[m][n] = __builtin_amdgcn_mfma_f32_16x16x32_bf16(af[m], buf_[n], accu[m][n], 0, 0, 0);
      }
    cur ^= 1;
  }

  // epilogue: h = u * silu(g) -> bf16
#pragma unroll
  for (int m = 0; m < 4; m++)
#pragma unroll
    for (int n = 0; n < 4; n++)
#pragma unroll
      for (int r = 0; r < 4; r++) {
        unsigned int grow = rb * 128u + wr * 64 + m * 16 + (lane >> 4) * 4 + r;
        if (grow < cnt) {
          float g = accg[m][n][r], u = accu[m][n][r];
          float h = u * g / (1.f + __expf(-g));
          int ic = i0 + wc * 64 + n * 16 + (lane & 15);
          hc[(size_t)(o + grow) * I_DIM + ic] = f2bf(h);
        }
      }
}

// ---------------- GEMM2: y[slot] = gate * (h @ w2[e]^T) (compact, no atomics) ----------------
// tile 128 rows x 128 h-cols, BK=32, 4 waves 2x2, dbuf + prefetch, swizzled.
__launch_bounds__(256, 2)
__global__ void k_gemm2(const unsigned short* __restrict__ hc, const unsigned short* __restrict__ w2b,
                        const unsigned int* __restrict__ off, const unsigned int* __restrict__ counts,
                        const float* __restrict__ rowgate, float* __restrict__ y) {
  int e = blockIdx.z;
  unsigned int cnt = counts[e];
  unsigned int rb = blockIdx.y;
  if (rb * 128u >= cnt) return;
  unsigned int o = off[e];
  int h0 = blockIdx.x * 128;

  // per buffer: A[128][32] @0, B[128][32] @4096 (shorts)
  __shared__ unsigned short lds[2][8192];  // 32 KB

  int tid = threadIdx.x, lane = tid & 63, wave = tid >> 6;
  int wr = wave >> 1, wc = wave & 1;

  const unsigned short *aptr[2], *bptr[2];
#pragma unroll
  for (int it = 0; it < 2; it++) {
    int flat = it * 256 + tid;
    int row = flat >> 2, q = flat & 3;
    int qs = q ^ ((row >> 1) & 3);
    unsigned int pos = rb * 128u + (unsigned int)row;
    unsigned int posc = (pos < cnt ? pos : cnt - 1u);
    aptr[it] = hc + (size_t)(o + posc) * I_DIM + qs * 8;
    bptr[it] = w2b + ((size_t)e * H_DIM + h0 + row) * I_DIM + qs * 8;
  }

  f32x4 acc[4][4];
#pragma unroll
  for (int m = 0; m < 4; m++)
#pragma unroll
    for (int n = 0; n < 4; n++) acc[m][n] = f32x4{0.f, 0.f, 0.f, 0.f};

#pragma unroll
  for (int it = 0; it < 2; it++) {
    gload16(aptr[it], &lds[0][(it * 256 + tid) * 8]);
    gload16(bptr[it], &lds[0][4096 + (it * 256 + tid) * 8]);
  }

  int cur = 0;
  int qg = lane >> 4;
  for (int step = 0; step < I_DIM / 32; ++step) {
    __syncthreads();
    if (step + 1 < I_DIM / 32) {
      int k0 = (step + 1) * 32;
#pragma unroll
      for (int it = 0; it < 2; it++) {
        gload16(aptr[it] + k0, &lds[cur ^ 1][(it * 256 + tid) * 8]);
        gload16(bptr[it] + k0, &lds[cur ^ 1][4096 + (it * 256 + tid) * 8]);
      }
    }
    bf16x8 af[4], bf[4];
#pragma unroll
    for (int m = 0; m < 4; m++) {
      int row = wr * 64 + m * 16 + (lane & 15);
      af[m] = *reinterpret_cast<const bf16x8*>(&lds[cur][SWZ(row, qg)]);
    }
#pragma unroll
    for (int n = 0; n < 4; n++) {
      int c = wc * 64 + n * 16 + (lane & 15);
      bf[n] = *reinterpret_cast<const bf16x8*>(&lds[cur][4096 + SWZ(c, qg)]);
    }
#pragma unroll
    for (int m = 0; m < 4; m++)
#pragma unroll
      for (int n = 0; n < 4; n++)
        acc[m][n] = __builtin_amdgcn_mfma_f32_16x16x32_bf16(af[m], bf[n], acc[m][n], 0, 0, 0);
    cur ^= 1;
  }

  // epilogue: plain gated stores into compact slot-major y
#pragma unroll
  for (int m = 0; m < 4; m++)
#pragma unroll
    for (int r = 0; r < 4; r++) {
      unsigned int grow = rb * 128u + wr * 64 + m * 16 + (lane >> 4) * 4 + r;
      if (grow < cnt) {
        float gate = rowgate[o + grow];
        float* yrow = y + (size_t)(o + grow) * H_DIM + h0 + wc * 64;
#pragma unroll
        for (int n = 0; n < 4; n++) yrow[n * 16 + (lane & 15)] = gate * acc[m][n][r];
      }
    }
}

// ---------------- combine: out[t] = y[slot1(t)] + y[slot2(t)] ----------------
__global__ void k_combine(const float* __restrict__ y, const int* __restrict__ tok2slot,
                          float* __restrict__ out) {
  int t = blockIdx.x * 4 + (threadIdx.x >> 6);
  int lane = threadIdx.x & 63;
  const float* y1 = y + (size_t)tok2slot[t * 2 + 0] * H_DIM;
  const float* y2 = y + (size_t)tok2slot[t * 2 + 1] * H_DIM;
  float* orow = out + (size_t)t * H_DIM;
#pragma unroll
  for (int h = 0; h < H_DIM; h += 256) {
    int idx = h + lane * 4;
    float4 a = *reinterpret_cast<const float4*>(&y1[idx]);
    float4 b = *reinterpret_cast<const float4*>(&y2[idx]);
    float4 rsum{a.x + b.x, a.y + b.y, a.z + b.z, a.w + b.w};
    *reinterpret_cast<float4*>(&orow[idx]) = rsum;
  }
}

extern "C" void kernel_launch(void* const* d_in, const int* in_sizes, int n_in,
                              void* d_out, int out_size, void* d_ws, size_t ws_size,
                              hipStream_t stream) {
  const float* x  = (const float*)d_in[0];
  const float* rw = (const float*)d_in[1];
  const float* w1 = (const float*)d_in[2];
  const float* w2 = (const float*)d_in[3];
  float* out = (float*)d_out;

  char* ws = (char*)d_ws;
  unsigned int* counts = (unsigned int*)(ws + 0);
  unsigned int* cursor = (unsigned int*)(ws + 64);
  unsigned int* off    = (unsigned int*)(ws + 128);
  float* gates    = (float*)(ws + 4096);                 // 32 KB
  int*   idxs     = (int*)(ws + 4096 + 32768);           // 32 KB
  int*   rowlist  = (int*)(ws + 4096 + 65536);           // 32 KB
  float* rowgate  = (float*)(ws + 4096 + 98304);         // 32 KB
  int*   tok2slot = (int*)(ws + 4096 + 131072);          // 32 KB
  unsigned short* xb  = (unsigned short*)(ws + (1ull << 20));    // 16 MiB @ 1 MiB
  unsigned short* hc  = (unsigned short*)(ws + (17ull << 20));   // 16 MiB @ 17 MiB
  unsigned short* w1b = (unsigned short*)(ws + (34ull << 20));   // 64 MiB @ 34 MiB
  unsigned short* w2b = (unsigned short*)(ws + (100ull << 20));  // 32 MiB @ 100 MiB
  float* y = (float*)(ws + (34ull << 20));  // 64 MiB, overlays w1b (dead after gemm1)

  hipMemsetAsync(ws, 0, 4096, stream);

  k_cvt_w1<<<(E_NUM * 2 * I_DIM * (H_DIM / 8) + 255) / 256, 256, 0, stream>>>(w1, w1b);
  k_cvt_w2<<<(E_NUM * H_DIM * (I_DIM / 8) + 255) / 256, 256, 0, stream>>>(w2, w2b);

  k_router<<<T_TOK, 64, 0, stream>>>(x, rw, gates, idxs, counts, xb);
  k_offsets<<<1, 64, 0, stream>>>(counts, off, cursor);
  k_scatter<<<T_TOK / 256, 256, 0, stream>>>(gates, idxs, cursor, rowlist, rowgate, tok2slot);
  k_gemm1<<<dim3(I_DIM / 128, T_TOK / 128, E_NUM), 256, 0, stream>>>(xb, w1b, off, counts, rowlist, hc);
  k_gemm2<<<dim3(H_DIM / 128, T_TOK / 128, E_NUM), 256, 0, stream>>>(hc, w2b, off, counts, rowgate, y);
  k_combine<<<T_TOK / 4, 256, 0, stream>>>(y, tok2slot, out);
}